// Round 6
// baseline (2764.406 us; speedup 1.0000x reference)
//
#include <hip/hip_runtime.h>
#include <stdint.h>

#define N_ELEM 262144
#define NC 512      /* coarse scatter buckets */
#define NFINE 16384 /* fine bins = NC * 32 */
#define TILE 32768
#define NBLK (N_ELEM / TILE) /* 8 */
#define CAP 4096 /* LDS capacity per coarse bucket; center ~3300 expected */

__device__ __forceinline__ unsigned key_of(float x) {
    unsigned u = __float_as_uint(x);
    return u ^ ((u & 0x80000000u) ? 0xFFFFFFFFu : 0x80000000u);
}

// Monotone (non-decreasing) float -> fine bin in [0, 16384). floor((x+8)*1024)
// is monotone; clamping only affects load balance, never correctness (in-bin
// compares use exact keys). coarse = fine>>5, sub = fine&31.
__device__ __forceinline__ int fine_of(float x) {
    int f = (int)floorf((x + 8.0f) * 1024.0f);
    f = f < 0 ? 0 : (f > NFINE - 1 ? NFINE - 1 : f);
    return f;
}

// --- Kernel A: per-(rowside,block) histogram of 512 coarse buckets ---------
__global__ __launch_bounds__(256) void hist_kernel(
    const float* __restrict__ pred, const float* __restrict__ tru, int r0,
    unsigned* __restrict__ bh) {
    __shared__ unsigned h[NC];
    const int rs = blockIdx.y, blk = blockIdx.x;
    const int row = r0 + (rs >> 1);
    const float* x = (rs & 1) ? tru : pred;
    for (int i = threadIdx.x; i < NC; i += 256) h[i] = 0;
    __syncthreads();
    const float4* p =
        (const float4*)(x + (size_t)row * N_ELEM + (size_t)blk * TILE);
    for (int i = threadIdx.x; i < TILE / 4; i += 256) {
        float4 v = p[i];
        atomicAdd(&h[fine_of(v.x) >> 5], 1u);
        atomicAdd(&h[fine_of(v.y) >> 5], 1u);
        atomicAdd(&h[fine_of(v.z) >> 5], 1u);
        atomicAdd(&h[fine_of(v.w) >> 5], 1u);
    }
    __syncthreads();
    unsigned* out = bh + ((size_t)rs * NBLK + blk) * NC;
    for (int i = threadIdx.x; i < NC; i += 256) out[i] = h[i];
}

// --- Kernel B: per-rowside scan -> per-block scatter starts ----------------
// After this, the blk-0 plane holds the rowside-level coarse exclusive prefix.
__global__ __launch_bounds__(512) void scan_kernel(unsigned* __restrict__ bh) {
    __shared__ unsigned ss[NC];
    const int rs = blockIdx.x;
    unsigned* p = bh + (size_t)rs * NBLK * NC;
    const int c = threadIdx.x; // one thread per coarse bucket
    unsigned cnts[NBLK];
    unsigned tot = 0;
    for (int b = 0; b < NBLK; b++) {
        cnts[b] = p[(size_t)b * NC + c];
        tot += cnts[b];
    }
    ss[c] = tot;
    __syncthreads();
    for (int off = 1; off < NC; off <<= 1) {
        unsigned v = (c >= off) ? ss[c - off] : 0u;
        __syncthreads();
        ss[c] += v;
        __syncthreads();
    }
    unsigned pre = ss[c] - tot; // exclusive
    for (int b = 0; b < NBLK; b++) {
        p[(size_t)b * NC + c] = pre;
        pre += cnts[b];
    }
}

// --- Kernel C: scatter (key, sub<<18|idx) grouped by coarse bucket ---------
// 1D grid, XCD-pinned by row: blockIdx%8 == row%8 so a row's rec lines are
// owned by one XCD's L2. q in [0,16): side=q&1, blk=q>>1.
__global__ __launch_bounds__(256) void scatter_kernel(
    const float* __restrict__ pred, const float* __restrict__ tru, int r0,
    int RR, const unsigned* __restrict__ bh, uint2* __restrict__ rec) {
    __shared__ unsigned cur[NC];
    const int L = blockIdx.x;
    const int xcd = L & 7;
    const int m = L >> 3;
    const int q = m & 15;
    const int rowGroup = m >> 4;
    const int crow = rowGroup * 8 + xcd;
    if (crow >= RR) return;
    const int side = q & 1, blk = q >> 1;
    const int rs = crow * 2 + side;
    const int row = r0 + crow;
    const float* x = side ? tru : pred;
    const unsigned* st = bh + ((size_t)rs * NBLK + blk) * NC;
    for (int i = threadIdx.x; i < NC; i += 256) cur[i] = st[i];
    __syncthreads();
    const float4* p =
        (const float4*)(x + (size_t)row * N_ELEM + (size_t)blk * TILE);
    uint2* rr = rec + (size_t)rs * N_ELEM;
    const int ib = blk * TILE;
    for (int i = threadIdx.x; i < TILE / 4; i += 256) {
        float4 v = p[i];
        int i0 = ib + i * 4;
        float vv[4] = {v.x, v.y, v.z, v.w};
#pragma unroll
        for (int k = 0; k < 4; k++) {
            int f = fine_of(vv[k]);
            unsigned pos = atomicAdd(&cur[f >> 5], 1u);
            unsigned meta = ((unsigned)(f & 31) << 18) | (unsigned)(i0 + k);
            unsigned long long packed =
                ((unsigned long long)meta << 32) | (unsigned long long)key_of(vv[k]);
            __builtin_nontemporal_store(packed, (unsigned long long*)&rr[pos]);
        }
    }
}

// --- Kernel D: per coarse bucket: LDS counting-sort by 5-bit sub-bin, then
// exact in-sub-bin ordinal rank. 1D grid, XCD-pinned by row so all rp[idx]
// scatter writes (side 0) / gathers (side 1) for a row stay in one L2.
// side==0: write rank into rp0[idx]; side==1: gather rp0[idx], acc S[row].
__global__ __launch_bounds__(256) void rank_kernel(
    const uint2* __restrict__ rec, const unsigned* __restrict__ bh,
    unsigned* __restrict__ rp0, unsigned long long* __restrict__ S, int r0,
    int RR, int side) {
    const int L = blockIdx.x;
    const int xcd = L & 7;
    const int m = L >> 3;
    const int c = m & (NC - 1);
    const int rowGroup = m / NC;
    const int crow = rowGroup * 8 + xcd;
    if (crow >= RR) return;
    const int rs = crow * 2 + side;
    const unsigned* pf = bh + (size_t)rs * NBLK * NC; // blk0 = rowside prefix
    const unsigned base = pf[c];
    const unsigned end = (c + 1 < NC) ? pf[c + 1] : (unsigned)N_ELEM;
    const int n = (int)(end - base);
    const int t = threadIdx.x;
    const uint2* r = rec + (size_t)rs * N_ELEM + base;
    unsigned* rp = rp0 + (size_t)crow * N_ELEM;
    unsigned long long acc = 0;
    __shared__ unsigned long long red[4];

    if (n > 0 && n <= CAP) {
        __shared__ unsigned skS[CAP], syS[CAP];
        __shared__ unsigned cnt[32], bas[33], curq[32];
        if (t < 32) cnt[t] = 0;
        __syncthreads();
        for (int p = t; p < n; p += 256)
            atomicAdd(&cnt[(r[p].y >> 18) & 31], 1u);
        __syncthreads();
        if (t == 0) {
            unsigned s = 0;
            for (int i = 0; i < 32; i++) {
                bas[i] = s;
                s += cnt[i];
            }
            bas[32] = s;
        }
        __syncthreads();
        if (t < 32) curq[t] = bas[t];
        __syncthreads();
        for (int p = t; p < n; p += 256) {
            uint2 e = r[p];
            unsigned pos = atomicAdd(&curq[(e.y >> 18) & 31], 1u);
            skS[pos] = e.x;
            syS[pos] = e.y;
        }
        __syncthreads();
        for (int p = t; p < n; p += 256) {
            unsigned y = syS[p];
            unsigned sub = (y >> 18) & 31;
            unsigned lo = bas[sub], hi = bas[sub + 1];
            unsigned long long myK =
                ((unsigned long long)skS[p] << 32) | (unsigned)p;
            unsigned cb = 0;
            for (unsigned k = lo; k < hi; k++) {
                unsigned long long K =
                    ((unsigned long long)skS[k] << 32) | k;
                cb += (K < myK) ? 1u : 0u;
            }
            unsigned rank = base + lo + cb + 1u;
            unsigned idx = y & 0x3FFFFu;
            if (!side)
                rp[idx] = rank;
            else
                acc += (unsigned long long)rp[idx] * (unsigned long long)rank;
        }
    } else if (n > CAP) { // safety fallback (not expected for N(0,1) inputs)
        for (int p = t; p < n; p += 256) {
            uint2 e = r[p];
            unsigned sub = (e.y >> 18) & 31;
            unsigned cb = 0;
            for (int k = 0; k < n; k++) {
                uint2 ek = r[k];
                unsigned s2 = (ek.y >> 18) & 31;
                bool less =
                    (s2 < sub) ||
                    (s2 == sub &&
                     (ek.x < e.x || (ek.x == e.x && k < p)));
                cb += less ? 1u : 0u;
            }
            unsigned rank = base + cb + 1u;
            unsigned idx = e.y & 0x3FFFFu;
            if (!side)
                rp[idx] = rank;
            else
                acc += (unsigned long long)rp[idx] * (unsigned long long)rank;
        }
    }
    if (side) {
        for (int off = 32; off > 0; off >>= 1)
            acc += __shfl_down(acc, off, 64);
        if ((t & 63) == 0) red[t >> 6] = acc;
        __syncthreads();
        if (t == 0) {
            unsigned long long s = red[0] + red[1] + red[2] + red[3];
            if (s) atomicAdd(&S[r0 + crow], s);
        }
    }
}

// --- Kernel E: closed-form Pearson of two exact permutations + loss --------
__global__ void finalize_kernel(const unsigned long long* __restrict__ S, int B,
                                float* __restrict__ out) {
    __shared__ double sh[128];
    const int t = threadIdx.x;
    const double Nd = (double)N_ELEM;
    const double m = (Nd + 1.0) * 0.5;
    const double q = Nd * (Nd * Nd - 1.0) / 12.0;
    double c = 0.0;
    if (t < B) {
        double num = (double)(long long)S[t] - Nd * m * m;
        c = num / sqrt(q * q + 1e-8);
    }
    sh[t] = c;
    __syncthreads();
    for (int off = 64; off > 0; off >>= 1) {
        if (t < off) sh[t] += sh[t + off];
        __syncthreads();
    }
    double mean = sh[0] / (double)B;
    __syncthreads();
    double d = (t < B) ? (c - mean) : 0.0;
    sh[t] = d * d;
    __syncthreads();
    for (int off = 64; off > 0; off >>= 1) {
        if (t < off) sh[t] += sh[t + off];
        __syncthreads();
    }
    if (t == 0) {
        double var = sh[0] / (double)B;
        double stdv = sqrt(var) + 1e-8;
        double icir = mean / stdv;
        out[0] = (float)(-icir + 0.1 * stdv);
    }
}

extern "C" void kernel_launch(void* const* d_in, const int* in_sizes, int n_in,
                              void* d_out, int out_size, void* d_ws,
                              size_t ws_size, hipStream_t stream) {
    const float* pred = (const float*)d_in[0];
    const float* tru = (const float*)d_in[1];
    const int B = in_sizes[0] / N_ELEM; // 90

    char* ws = (char*)d_ws;
    unsigned long long* S = (unsigned long long*)ws;
    const size_t off0 = 4096;
    // per chunked row: bh 2*8*512*4 = 32KB, rec both sides 4MB, rp0 1MB
    const size_t bhRow = (size_t)2 * NBLK * NC * 4;
    const size_t recRow = (size_t)2 * N_ELEM * 8;
    const size_t rpRow = (size_t)N_ELEM * 4;
    const size_t perRow = bhRow + recRow + rpRow;
    int R = (int)((ws_size > off0 ? ws_size - off0 : 0) / perRow);
    if (R > B) R = B;
    if (R < 1) R = 1;

    unsigned* bh = (unsigned*)(ws + off0);
    uint2* rec = (uint2*)(ws + off0 + (size_t)R * bhRow);
    unsigned* rp0 = (unsigned*)(ws + off0 + (size_t)R * bhRow + (size_t)R * recRow);

    hipMemsetAsync(S, 0, (size_t)B * 8, stream);

    for (int r0 = 0; r0 < B; r0 += R) {
        int RR = (B - r0 < R) ? (B - r0) : R;
        int rowGroups = (RR + 7) / 8;
        hist_kernel<<<dim3(NBLK, 2 * RR), 256, 0, stream>>>(pred, tru, r0, bh);
        scan_kernel<<<2 * RR, NC, 0, stream>>>(bh);
        scatter_kernel<<<rowGroups * 16 * 8, 256, 0, stream>>>(pred, tru, r0,
                                                               RR, bh, rec);
        rank_kernel<<<rowGroups * NC * 8, 256, 0, stream>>>(rec, bh, rp0, S,
                                                            r0, RR, 0);
        rank_kernel<<<rowGroups * NC * 8, 256, 0, stream>>>(rec, bh, rp0, S,
                                                            r0, RR, 1);
    }
    finalize_kernel<<<1, 128, 0, stream>>>(S, B, (float*)d_out);
}

// Round 7
// 1302.826 us; speedup vs baseline: 2.1219x; 2.1219x over previous
//
#include <hip/hip_runtime.h>
#include <stdint.h>

#define N_ELEM 262144
#define NC 512      /* coarse scatter buckets */
#define NFINE 16384 /* fine bins = NC * 32 */
#define TILE 32768
#define NBLK (N_ELEM / TILE) /* 8 */
#define CAP 4096 /* LDS capacity per coarse bucket; center ~3300 expected */

__device__ __forceinline__ unsigned key_of(float x) {
    unsigned u = __float_as_uint(x);
    return u ^ ((u & 0x80000000u) ? 0xFFFFFFFFu : 0x80000000u);
}

// Monotone (non-decreasing) float -> fine bin in [0, 16384). floor((x+8)*1024)
// is monotone; clamping only affects load balance, never correctness (in-bin
// compares use exact keys). coarse = fine>>5, sub = fine&31.
__device__ __forceinline__ int fine_of(float x) {
    int f = (int)floorf((x + 8.0f) * 1024.0f);
    f = f < 0 ? 0 : (f > NFINE - 1 ? NFINE - 1 : f);
    return f;
}

// --- Kernel A: per-(rowside,block) histogram of 512 coarse buckets ---------
__global__ __launch_bounds__(256) void hist_kernel(
    const float* __restrict__ pred, const float* __restrict__ tru, int r0,
    unsigned* __restrict__ bh) {
    __shared__ unsigned h[NC];
    const int rs = blockIdx.y, blk = blockIdx.x;
    const int row = r0 + (rs >> 1);
    const float* x = (rs & 1) ? tru : pred;
    for (int i = threadIdx.x; i < NC; i += 256) h[i] = 0;
    __syncthreads();
    const float4* p =
        (const float4*)(x + (size_t)row * N_ELEM + (size_t)blk * TILE);
    for (int i = threadIdx.x; i < TILE / 4; i += 256) {
        float4 v = p[i];
        atomicAdd(&h[fine_of(v.x) >> 5], 1u);
        atomicAdd(&h[fine_of(v.y) >> 5], 1u);
        atomicAdd(&h[fine_of(v.z) >> 5], 1u);
        atomicAdd(&h[fine_of(v.w) >> 5], 1u);
    }
    __syncthreads();
    unsigned* out = bh + ((size_t)rs * NBLK + blk) * NC;
    for (int i = threadIdx.x; i < NC; i += 256) out[i] = h[i];
}

// --- Kernel B: per-rowside scan -> per-block scatter starts ----------------
// After this, the blk-0 plane holds the rowside-level coarse exclusive prefix.
__global__ __launch_bounds__(512) void scan_kernel(unsigned* __restrict__ bh) {
    __shared__ unsigned ss[NC];
    const int rs = blockIdx.x;
    unsigned* p = bh + (size_t)rs * NBLK * NC;
    const int c = threadIdx.x; // one thread per coarse bucket
    unsigned cnts[NBLK];
    unsigned tot = 0;
    for (int b = 0; b < NBLK; b++) {
        cnts[b] = p[(size_t)b * NC + c];
        tot += cnts[b];
    }
    ss[c] = tot;
    __syncthreads();
    for (int off = 1; off < NC; off <<= 1) {
        unsigned v = (c >= off) ? ss[c - off] : 0u;
        __syncthreads();
        ss[c] += v;
        __syncthreads();
    }
    unsigned pre = ss[c] - tot; // exclusive
    for (int b = 0; b < NBLK; b++) {
        p[(size_t)b * NC + c] = pre;
        pre += cnts[b];
    }
}

// --- Kernel C: scatter (key, sub<<18|idx) grouped by coarse bucket ---------
// 1D grid, XCD-pinned by row (blockIdx%8 heuristic): a row's rec lines are
// dirtied in one XCD's L2 only. Plain stores — L2 accumulates full lines
// (the R6 nontemporal-store experiment showed nt => 3.5x HBM write amp).
__global__ __launch_bounds__(256) void scatter_kernel(
    const float* __restrict__ pred, const float* __restrict__ tru, int r0,
    int RR, const unsigned* __restrict__ bh, uint2* __restrict__ rec) {
    __shared__ unsigned cur[NC];
    const int L = blockIdx.x;
    const int xcd = L & 7;
    const int m = L >> 3;
    const int q = m & 15;
    const int rowGroup = m >> 4;
    const int crow = rowGroup * 8 + xcd;
    if (crow >= RR) return;
    const int side = q & 1, blk = q >> 1;
    const int rs = crow * 2 + side;
    const int row = r0 + crow;
    const float* x = side ? tru : pred;
    const unsigned* st = bh + ((size_t)rs * NBLK + blk) * NC;
    for (int i = threadIdx.x; i < NC; i += 256) cur[i] = st[i];
    __syncthreads();
    const float4* p =
        (const float4*)(x + (size_t)row * N_ELEM + (size_t)blk * TILE);
    uint2* rr = rec + (size_t)rs * N_ELEM;
    const int ib = blk * TILE;
    for (int i = threadIdx.x; i < TILE / 4; i += 256) {
        float4 v = p[i];
        int i0 = ib + i * 4;
        float vv[4] = {v.x, v.y, v.z, v.w};
#pragma unroll
        for (int k = 0; k < 4; k++) {
            int f = fine_of(vv[k]);
            unsigned pos = atomicAdd(&cur[f >> 5], 1u);
            rr[pos] = make_uint2(
                key_of(vv[k]),
                ((unsigned)(f & 31) << 18) | (unsigned)(i0 + k));
        }
    }
}

// --- Kernel D: per coarse bucket: LDS counting-sort by 5-bit sub-bin, then
// exact in-sub-bin ordinal rank. 1D grid, XCD-pinned by row so all rp[idx]
// scatter writes (side 0) / gathers (side 1) for a row stay in one L2.
// side==0: write rank into rp0[idx]; side==1: gather rp0[idx], acc S[row].
__global__ __launch_bounds__(256) void rank_kernel(
    const uint2* __restrict__ rec, const unsigned* __restrict__ bh,
    unsigned* __restrict__ rp0, unsigned long long* __restrict__ S, int r0,
    int RR, int side) {
    const int L = blockIdx.x;
    const int xcd = L & 7;
    const int m = L >> 3;
    const int c = m & (NC - 1);
    const int rowGroup = m / NC;
    const int crow = rowGroup * 8 + xcd;
    if (crow >= RR) return;
    const int rs = crow * 2 + side;
    const unsigned* pf = bh + (size_t)rs * NBLK * NC; // blk0 = rowside prefix
    const unsigned base = pf[c];
    const unsigned end = (c + 1 < NC) ? pf[c + 1] : (unsigned)N_ELEM;
    const int n = (int)(end - base);
    const int t = threadIdx.x;
    const uint2* r = rec + (size_t)rs * N_ELEM + base;
    unsigned* rp = rp0 + (size_t)crow * N_ELEM;
    unsigned long long acc = 0;
    __shared__ unsigned long long red[4];

    if (n > 0 && n <= CAP) {
        __shared__ unsigned skS[CAP], syS[CAP];
        __shared__ unsigned cnt[32], bas[33], curq[32];
        if (t < 32) cnt[t] = 0;
        __syncthreads();
        for (int p = t; p < n; p += 256)
            atomicAdd(&cnt[(r[p].y >> 18) & 31], 1u);
        __syncthreads();
        if (t == 0) {
            unsigned s = 0;
            for (int i = 0; i < 32; i++) {
                bas[i] = s;
                s += cnt[i];
            }
            bas[32] = s;
        }
        __syncthreads();
        if (t < 32) curq[t] = bas[t];
        __syncthreads();
        for (int p = t; p < n; p += 256) {
            uint2 e = r[p];
            unsigned pos = atomicAdd(&curq[(e.y >> 18) & 31], 1u);
            skS[pos] = e.x;
            syS[pos] = e.y;
        }
        __syncthreads();
        for (int p = t; p < n; p += 256) {
            unsigned y = syS[p];
            unsigned sub = (y >> 18) & 31;
            unsigned lo = bas[sub], hi = bas[sub + 1];
            unsigned long long myK =
                ((unsigned long long)skS[p] << 32) | (unsigned)p;
            unsigned cb = 0;
            for (unsigned k = lo; k < hi; k++) {
                unsigned long long K =
                    ((unsigned long long)skS[k] << 32) | k;
                cb += (K < myK) ? 1u : 0u;
            }
            unsigned rank = base + lo + cb + 1u;
            unsigned idx = y & 0x3FFFFu;
            if (!side)
                rp[idx] = rank;
            else
                acc += (unsigned long long)rp[idx] * (unsigned long long)rank;
        }
    } else if (n > CAP) { // safety fallback (not expected for N(0,1) inputs)
        for (int p = t; p < n; p += 256) {
            uint2 e = r[p];
            unsigned sub = (e.y >> 18) & 31;
            unsigned cb = 0;
            for (int k = 0; k < n; k++) {
                uint2 ek = r[k];
                unsigned s2 = (ek.y >> 18) & 31;
                bool less =
                    (s2 < sub) ||
                    (s2 == sub &&
                     (ek.x < e.x || (ek.x == e.x && k < p)));
                cb += less ? 1u : 0u;
            }
            unsigned rank = base + cb + 1u;
            unsigned idx = e.y & 0x3FFFFu;
            if (!side)
                rp[idx] = rank;
            else
                acc += (unsigned long long)rp[idx] * (unsigned long long)rank;
        }
    }
    if (side) {
        for (int off = 32; off > 0; off >>= 1)
            acc += __shfl_down(acc, off, 64);
        if ((t & 63) == 0) red[t >> 6] = acc;
        __syncthreads();
        if (t == 0) {
            unsigned long long s = red[0] + red[1] + red[2] + red[3];
            if (s) atomicAdd(&S[r0 + crow], s);
        }
    }
}

// --- Kernel E: closed-form Pearson of two exact permutations + loss --------
__global__ void finalize_kernel(const unsigned long long* __restrict__ S, int B,
                                float* __restrict__ out) {
    __shared__ double sh[128];
    const int t = threadIdx.x;
    const double Nd = (double)N_ELEM;
    const double m = (Nd + 1.0) * 0.5;
    const double q = Nd * (Nd * Nd - 1.0) / 12.0;
    double c = 0.0;
    if (t < B) {
        double num = (double)(long long)S[t] - Nd * m * m;
        c = num / sqrt(q * q + 1e-8);
    }
    sh[t] = c;
    __syncthreads();
    for (int off = 64; off > 0; off >>= 1) {
        if (t < off) sh[t] += sh[t + off];
        __syncthreads();
    }
    double mean = sh[0] / (double)B;
    __syncthreads();
    double d = (t < B) ? (c - mean) : 0.0;
    sh[t] = d * d;
    __syncthreads();
    for (int off = 64; off > 0; off >>= 1) {
        if (t < off) sh[t] += sh[t + off];
        __syncthreads();
    }
    if (t == 0) {
        double var = sh[0] / (double)B;
        double stdv = sqrt(var) + 1e-8;
        double icir = mean / stdv;
        out[0] = (float)(-icir + 0.1 * stdv);
    }
}

extern "C" void kernel_launch(void* const* d_in, const int* in_sizes, int n_in,
                              void* d_out, int out_size, void* d_ws,
                              size_t ws_size, hipStream_t stream) {
    const float* pred = (const float*)d_in[0];
    const float* tru = (const float*)d_in[1];
    const int B = in_sizes[0] / N_ELEM; // 90

    char* ws = (char*)d_ws;
    unsigned long long* S = (unsigned long long*)ws;
    const size_t off0 = 4096;
    // per chunked row: bh 2*8*512*4 = 32KB, rec both sides 4MB, rp0 1MB
    const size_t bhRow = (size_t)2 * NBLK * NC * 4;
    const size_t recRow = (size_t)2 * N_ELEM * 8;
    const size_t rpRow = (size_t)N_ELEM * 4;
    const size_t perRow = bhRow + recRow + rpRow;
    int R = (int)((ws_size > off0 ? ws_size - off0 : 0) / perRow);
    if (R > B) R = B;
    if (R < 1) R = 1;

    unsigned* bh = (unsigned*)(ws + off0);
    uint2* rec = (uint2*)(ws + off0 + (size_t)R * bhRow);
    unsigned* rp0 = (unsigned*)(ws + off0 + (size_t)R * bhRow + (size_t)R * recRow);

    hipMemsetAsync(S, 0, (size_t)B * 8, stream);

    for (int r0 = 0; r0 < B; r0 += R) {
        int RR = (B - r0 < R) ? (B - r0) : R;
        int rowGroups = (RR + 7) / 8;
        hist_kernel<<<dim3(NBLK, 2 * RR), 256, 0, stream>>>(pred, tru, r0, bh);
        scan_kernel<<<2 * RR, NC, 0, stream>>>(bh);
        scatter_kernel<<<rowGroups * 16 * 8, 256, 0, stream>>>(pred, tru, r0,
                                                               RR, bh, rec);
        rank_kernel<<<rowGroups * NC * 8, 256, 0, stream>>>(rec, bh, rp0, S,
                                                            r0, RR, 0);
        rank_kernel<<<rowGroups * NC * 8, 256, 0, stream>>>(rec, bh, rp0, S,
                                                            r0, RR, 1);
    }
    finalize_kernel<<<1, 128, 0, stream>>>(S, B, (float*)d_out);
}

// Round 8
// 1124.338 us; speedup vs baseline: 2.4587x; 1.1587x over previous
//
#include <hip/hip_runtime.h>
#include <stdint.h>

#define N_ELEM 262144
#define NC 512       /* coarse scatter buckets */
#define NFINE 131072 /* fine bins = NC * 256; lambda ~2 at center */
#define TILE 32768
#define NBLK (N_ELEM / TILE) /* 8 */
#define CAP 4096 /* LDS capacity per coarse bucket; center ~3300 expected */

__device__ __forceinline__ unsigned key_of(float x) {
    unsigned u = __float_as_uint(x);
    return u ^ ((u & 0x80000000u) ? 0xFFFFFFFFu : 0x80000000u);
}

// Monotone (non-decreasing) float -> fine bin in [0, 131072).
// floor((x+8)*8192) is monotone (*8192 exact); clamping only affects load
// balance, never correctness (in-bin compares use exact keys).
// coarse = fine>>8 (512), sub = fine&255.
__device__ __forceinline__ int fine_of(float x) {
    int f = (int)floorf((x + 8.0f) * 8192.0f);
    f = f < 0 ? 0 : (f > NFINE - 1 ? NFINE - 1 : f);
    return f;
}

// --- Kernel A: per-(rowside,block) histogram of 512 coarse buckets ---------
__global__ __launch_bounds__(256) void hist_kernel(
    const float* __restrict__ pred, const float* __restrict__ tru, int r0,
    unsigned* __restrict__ bh) {
    __shared__ unsigned h[NC];
    const int rs = blockIdx.y, blk = blockIdx.x;
    const int row = r0 + (rs >> 1);
    const float* x = (rs & 1) ? tru : pred;
    for (int i = threadIdx.x; i < NC; i += 256) h[i] = 0;
    __syncthreads();
    const float4* p =
        (const float4*)(x + (size_t)row * N_ELEM + (size_t)blk * TILE);
    for (int i = threadIdx.x; i < TILE / 4; i += 256) {
        float4 v = p[i];
        atomicAdd(&h[fine_of(v.x) >> 8], 1u);
        atomicAdd(&h[fine_of(v.y) >> 8], 1u);
        atomicAdd(&h[fine_of(v.z) >> 8], 1u);
        atomicAdd(&h[fine_of(v.w) >> 8], 1u);
    }
    __syncthreads();
    unsigned* out = bh + ((size_t)rs * NBLK + blk) * NC;
    for (int i = threadIdx.x; i < NC; i += 256) out[i] = h[i];
}

// --- Kernel B: per-rowside scan -> per-block scatter starts ----------------
// After this, the blk-0 plane holds the rowside-level coarse exclusive prefix.
__global__ __launch_bounds__(512) void scan_kernel(unsigned* __restrict__ bh) {
    __shared__ unsigned ss[NC];
    const int rs = blockIdx.x;
    unsigned* p = bh + (size_t)rs * NBLK * NC;
    const int c = threadIdx.x; // one thread per coarse bucket
    unsigned cnts[NBLK];
    unsigned tot = 0;
    for (int b = 0; b < NBLK; b++) {
        cnts[b] = p[(size_t)b * NC + c];
        tot += cnts[b];
    }
    ss[c] = tot;
    __syncthreads();
    for (int off = 1; off < NC; off <<= 1) {
        unsigned v = (c >= off) ? ss[c - off] : 0u;
        __syncthreads();
        ss[c] += v;
        __syncthreads();
    }
    unsigned pre = ss[c] - tot; // exclusive
    for (int b = 0; b < NBLK; b++) {
        p[(size_t)b * NC + c] = pre;
        pre += cnts[b];
    }
}

// --- Kernel C: scatter (key, sub<<18|idx) grouped by coarse bucket ---------
// 1D grid, XCD-pinned by row (blockIdx%8 heuristic): a row's rec lines are
// dirtied in one XCD's L2 only. Plain stores — L2 accumulates full lines
// (R6 showed nontemporal stores => 3.5x HBM write amplification).
__global__ __launch_bounds__(256) void scatter_kernel(
    const float* __restrict__ pred, const float* __restrict__ tru, int r0,
    int RR, const unsigned* __restrict__ bh, uint2* __restrict__ rec) {
    __shared__ unsigned cur[NC];
    const int L = blockIdx.x;
    const int xcd = L & 7;
    const int m = L >> 3;
    const int q = m & 15;
    const int rowGroup = m >> 4;
    const int crow = rowGroup * 8 + xcd;
    if (crow >= RR) return;
    const int side = q & 1, blk = q >> 1;
    const int rs = crow * 2 + side;
    const int row = r0 + crow;
    const float* x = side ? tru : pred;
    const unsigned* st = bh + ((size_t)rs * NBLK + blk) * NC;
    for (int i = threadIdx.x; i < NC; i += 256) cur[i] = st[i];
    __syncthreads();
    const float4* p =
        (const float4*)(x + (size_t)row * N_ELEM + (size_t)blk * TILE);
    uint2* rr = rec + (size_t)rs * N_ELEM;
    const int ib = blk * TILE;
    for (int i = threadIdx.x; i < TILE / 4; i += 256) {
        float4 v = p[i];
        int i0 = ib + i * 4;
        float vv[4] = {v.x, v.y, v.z, v.w};
#pragma unroll
        for (int k = 0; k < 4; k++) {
            int f = fine_of(vv[k]);
            unsigned pos = atomicAdd(&cur[f >> 8], 1u);
            rr[pos] = make_uint2(
                key_of(vv[k]),
                ((unsigned)(f & 255) << 18) | (unsigned)(i0 + k));
        }
    }
}

// --- Kernel D: per coarse bucket: LDS counting-sort by 8-bit sub-bin, then
// exact in-sub-bin ordinal rank (~9 compares/element weighted, lambda~2).
// 1D grid, XCD-pinned by row so rp[idx] writes (side 0) / gathers (side 1)
// stay in one L2. side==0: rp0[idx]=rank; side==1: gather, acc S[row].
__global__ __launch_bounds__(256) void rank_kernel(
    const uint2* __restrict__ rec, const unsigned* __restrict__ bh,
    unsigned* __restrict__ rp0, unsigned long long* __restrict__ S, int r0,
    int RR, int side) {
    const int L = blockIdx.x;
    const int xcd = L & 7;
    const int m = L >> 3;
    const int c = m & (NC - 1);
    const int rowGroup = m / NC;
    const int crow = rowGroup * 8 + xcd;
    if (crow >= RR) return;
    const int rs = crow * 2 + side;
    const unsigned* pf = bh + (size_t)rs * NBLK * NC; // blk0 = rowside prefix
    const unsigned base = pf[c];
    const unsigned end = (c + 1 < NC) ? pf[c + 1] : (unsigned)N_ELEM;
    const int n = (int)(end - base);
    const int t = threadIdx.x;
    const uint2* r = rec + (size_t)rs * N_ELEM + base;
    unsigned* rp = rp0 + (size_t)crow * N_ELEM;
    unsigned long long acc = 0;
    __shared__ unsigned long long red[4];

    if (n > 0 && n <= CAP) {
        __shared__ unsigned skS[CAP], syS[CAP];
        __shared__ unsigned cnt[256], bas[257], curq[256], ssc[256];
        cnt[t] = 0;
        __syncthreads();
        for (int p = t; p < n; p += 256)
            atomicAdd(&cnt[(r[p].y >> 18) & 255], 1u);
        __syncthreads();
        { // exclusive prefix over the 256 sub-bin counts (ladder scan)
            unsigned mine = cnt[t];
            ssc[t] = mine;
            __syncthreads();
            for (int off = 1; off < 256; off <<= 1) {
                unsigned v = (t >= off) ? ssc[t - off] : 0u;
                __syncthreads();
                ssc[t] += v;
                __syncthreads();
            }
            unsigned ex = ssc[t] - mine;
            bas[t] = ex;
            curq[t] = ex;
            if (t == 255) bas[256] = ssc[255];
        }
        __syncthreads();
        for (int p = t; p < n; p += 256) {
            uint2 e = r[p];
            unsigned pos = atomicAdd(&curq[(e.y >> 18) & 255], 1u);
            skS[pos] = e.x;
            syS[pos] = e.y;
        }
        __syncthreads();
        for (int p = t; p < n; p += 256) {
            unsigned y = syS[p];
            unsigned sub = (y >> 18) & 255;
            unsigned lo = bas[sub], hi = bas[sub + 1];
            unsigned myKey = skS[p];
            unsigned cb = 0;
            for (unsigned k = lo; k < hi; k++) {
                unsigned K = skS[k];
                cb += (K < myKey || (K == myKey && k < (unsigned)p)) ? 1u : 0u;
            }
            unsigned rank = base + lo + cb + 1u;
            unsigned idx = y & 0x3FFFFu;
            if (!side)
                rp[idx] = rank;
            else
                acc += (unsigned long long)rp[idx] * (unsigned long long)rank;
        }
    } else if (n > CAP) { // safety fallback (not expected for N(0,1) inputs)
        for (int p = t; p < n; p += 256) {
            uint2 e = r[p];
            unsigned sub = (e.y >> 18) & 255;
            unsigned cb = 0;
            for (int k = 0; k < n; k++) {
                uint2 ek = r[k];
                unsigned s2 = (ek.y >> 18) & 255;
                bool less =
                    (s2 < sub) ||
                    (s2 == sub &&
                     (ek.x < e.x || (ek.x == e.x && k < p)));
                cb += less ? 1u : 0u;
            }
            unsigned rank = base + cb + 1u;
            unsigned idx = e.y & 0x3FFFFu;
            if (!side)
                rp[idx] = rank;
            else
                acc += (unsigned long long)rp[idx] * (unsigned long long)rank;
        }
    }
    if (side) {
        for (int off = 32; off > 0; off >>= 1)
            acc += __shfl_down(acc, off, 64);
        if ((t & 63) == 0) red[t >> 6] = acc;
        __syncthreads();
        if (t == 0) {
            unsigned long long s = red[0] + red[1] + red[2] + red[3];
            if (s) atomicAdd(&S[r0 + crow], s);
        }
    }
}

// --- Kernel E: closed-form Pearson of two exact permutations + loss --------
__global__ void finalize_kernel(const unsigned long long* __restrict__ S, int B,
                                float* __restrict__ out) {
    __shared__ double sh[128];
    const int t = threadIdx.x;
    const double Nd = (double)N_ELEM;
    const double m = (Nd + 1.0) * 0.5;
    const double q = Nd * (Nd * Nd - 1.0) / 12.0;
    double c = 0.0;
    if (t < B) {
        double num = (double)(long long)S[t] - Nd * m * m;
        c = num / sqrt(q * q + 1e-8);
    }
    sh[t] = c;
    __syncthreads();
    for (int off = 64; off > 0; off >>= 1) {
        if (t < off) sh[t] += sh[t + off];
        __syncthreads();
    }
    double mean = sh[0] / (double)B;
    __syncthreads();
    double d = (t < B) ? (c - mean) : 0.0;
    sh[t] = d * d;
    __syncthreads();
    for (int off = 64; off > 0; off >>= 1) {
        if (t < off) sh[t] += sh[t + off];
        __syncthreads();
    }
    if (t == 0) {
        double var = sh[0] / (double)B;
        double stdv = sqrt(var) + 1e-8;
        double icir = mean / stdv;
        out[0] = (float)(-icir + 0.1 * stdv);
    }
}

extern "C" void kernel_launch(void* const* d_in, const int* in_sizes, int n_in,
                              void* d_out, int out_size, void* d_ws,
                              size_t ws_size, hipStream_t stream) {
    const float* pred = (const float*)d_in[0];
    const float* tru = (const float*)d_in[1];
    const int B = in_sizes[0] / N_ELEM; // 90

    char* ws = (char*)d_ws;
    unsigned long long* S = (unsigned long long*)ws;
    const size_t off0 = 4096;
    // per chunked row: bh 2*8*512*4 = 32KB, rec both sides 4MB, rp0 1MB
    const size_t bhRow = (size_t)2 * NBLK * NC * 4;
    const size_t recRow = (size_t)2 * N_ELEM * 8;
    const size_t rpRow = (size_t)N_ELEM * 4;
    const size_t perRow = bhRow + recRow + rpRow;
    int R = (int)((ws_size > off0 ? ws_size - off0 : 0) / perRow);
    if (R > B) R = B;
    if (R < 1) R = 1;

    unsigned* bh = (unsigned*)(ws + off0);
    uint2* rec = (uint2*)(ws + off0 + (size_t)R * bhRow);
    unsigned* rp0 = (unsigned*)(ws + off0 + (size_t)R * bhRow + (size_t)R * recRow);

    hipMemsetAsync(S, 0, (size_t)B * 8, stream);

    for (int r0 = 0; r0 < B; r0 += R) {
        int RR = (B - r0 < R) ? (B - r0) : R;
        int rowGroups = (RR + 7) / 8;
        hist_kernel<<<dim3(NBLK, 2 * RR), 256, 0, stream>>>(pred, tru, r0, bh);
        scan_kernel<<<2 * RR, NC, 0, stream>>>(bh);
        scatter_kernel<<<rowGroups * 16 * 8, 256, 0, stream>>>(pred, tru, r0,
                                                               RR, bh, rec);
        rank_kernel<<<rowGroups * NC * 8, 256, 0, stream>>>(rec, bh, rp0, S,
                                                            r0, RR, 0);
        rank_kernel<<<rowGroups * NC * 8, 256, 0, stream>>>(rec, bh, rp0, S,
                                                            r0, RR, 1);
    }
    finalize_kernel<<<1, 128, 0, stream>>>(S, B, (float*)d_out);
}